// Round 11
// baseline (116.357 us; speedup 1.0000x reference)
//
#include <hip/hip_runtime.h>
#include <hip/hip_bf16.h>
#include <hip/hip_cooperative_groups.h>

namespace cg = cooperative_groups;

// Problem constants
#define B_    64
#define C_    64
#define N_    22
#define T_    1024
#define O_    64
#define KTOT  1408      // C_*N_
#define KSTEPS 44       // KTOT/32

typedef __bf16 bf16x8 __attribute__((ext_vector_type(8)));
typedef float  f32x4  __attribute__((ext_vector_type(4)));

typedef __attribute__((address_space(1))) float f32_g;
typedef __attribute__((address_space(3))) float f32_l;

#define WAITV(N) asm volatile("s_waitcnt vmcnt(" #N ")" ::: "memory")
#define BARR do { __builtin_amdgcn_s_barrier(); __builtin_amdgcn_sched_barrier(0); } while (0)

// ---------------------------------------------------------------------------
// FUSED kernel (cooperative): phase A issues the first two x staging rounds
// (no prep dependency), phase B does the distributed prep (o = rawbid>>2,
// kq = rawbid&3; scratch overlaid in LDS buffer b2), grid.sync(), then
// phase C runs the EXACT R10 gemm loop (NT loads aux=18, NT stores,
// counted WAITV(4), source-side chunk-XOR swizzle, XCD-swizzled bid).
// ---------------------------------------------------------------------------
__global__ __launch_bounds__(512, 2) void fused_main(
    const float* __restrict__ x,
    const float* __restrict__ adjp,
    const float* __restrict__ chebw,   // [3][64][64]
    const float* __restrict__ chebb,   // [64]
    const float* __restrict__ aggw,    // [64][64][22]
    const float* __restrict__ aggb,    // [64]
    __bf16* __restrict__ Mfrag,        // [176*512] ws
    float* __restrict__ constv,        // [64] ws
    float* __restrict__ y)
{
    __shared__ float lds[3 * 8192];   // 3 x [32 k][256 t] fp32 = 96 KB

    const int tid  = threadIdx.x;
    // gemm ids: XCD swizzle (bijective, 256 % 8 == 0)
    const int bid  = ((blockIdx.x & 7) << 5) | (blockIdx.x >> 3);
    const int b    = bid >> 2;
    const int tq   = bid & 3;
    const int wave = tid >> 6;           // 0..7
    const int lane = tid & 63;
    const int tcol = lane & 15;
    const int kg   = lane >> 4;

    const size_t xbase = (size_t)b * ((size_t)KTOT * T_) + (size_t)tq * 256;

    float* const b0 = lds;
    float* const b1 = lds + 8192;
    float* const b2 = lds + 16384;

    // STAGE: wave stages rows wave*4+q (1 KB each); LDS dest linear,
    // source pre-swizzled; aux=18 = NT|SC1 (stream-once x).
    auto STAGE = [&](int ks, float* buf) {
#pragma unroll
        for (int q = 0; q < 4; ++q) {
            const int r = wave * 4 + q;
            const int s = (r >> 3) & 1;
            const int g = ((lane >> 2) ^ s);
            const float* src = x + xbase + (size_t)(ks * 32 + r) * T_
                             + g * 16 + (lane & 3) * 4;
            float* dst = buf + r * 256;
            __builtin_amdgcn_global_load_lds((const f32_g*)src, (f32_l*)dst, 16, 0, 18);
        }
    };

    // ======== Phase A: prefetch tiles 0,1 (independent of prep) ========
    STAGE(0, b0);
    STAGE(1, b1);

    // ======== Phase B: distributed prep (scratch in b2: 5728 floats) ====
    {
        const int po = blockIdx.x >> 2;   // raw ids for prep mapping
        const int kq = blockIdx.x & 3;
        float* smv  = b2;          // 484  s = -D^-1/2 A D^-1/2
        float* cm2  = b2 + 484;    // 484  adj, then C2 = 2 s^2 - I
        float* disv = b2 + 968;    // 22
        float* aggs = b2 + 992;    // 1408 aggw[po,:,:]
        float* F1   = b2 + 2400;   // 1408
        float* F2   = b2 + 3808;   // 1408
        float* red  = b2 + 5216;   // 512

        for (int e = tid; e < 484; e += 512) {
            int i = e / 22, j = e - i * 22;
            float a = 0.5f * (1.f / (1.f + expf(-adjp[i * 22 + j])) +
                              1.f / (1.f + expf(-adjp[j * 22 + i])));
            cm2[e] = (i == j) ? 0.f : a;
        }
        for (int e = tid; e < KTOT; e += 512) aggs[e] = aggw[po * KTOT + e];
        __syncthreads();
        if (tid < 22) {
            float d = 0.f;
            for (int n = 0; n < 22; ++n) d += cm2[tid * 22 + n];
            disv[tid] = rsqrtf(d);
        }
        __syncthreads();
        for (int e = tid; e < 484; e += 512) {
            int i = e / 22, j = e - i * 22;
            smv[e] = -disv[i] * cm2[e] * disv[j];
        }
        __syncthreads();
        for (int e = tid; e < 484; e += 512) {
            int i = e / 22, j = e - i * 22;
            float a2 = 0.f;
            for (int n = 0; n < 22; ++n) a2 += smv[i * 22 + n] * smv[n * 22 + j];
            cm2[e] = 2.f * a2 - (i == j ? 1.f : 0.f);
        }
        __syncthreads();
        for (int e = tid; e < KTOT; e += 512) {
            int cp = e / 22, v = e - cp * 22;
            float a1 = 0.f, a2 = 0.f;
            for (int n = 0; n < 22; ++n) {
                float w = aggs[cp * 22 + n];
                a1 += w * smv[n * 22 + v];
                a2 += w * cm2[n * 22 + v];
            }
            F1[e] = a1;
            F2[e] = a2;
        }
        if (kq == 0) {
            float p = 0.f;
            for (int e = tid; e < KTOT; e += 512) p += aggs[e] * chebb[e / 22];
            red[tid] = p;
        }
        __syncthreads();   // covers F1/F2 (all blocks) and red (kq==0)
        if (kq == 0) {     // block-uniform branch: barriers are safe
            for (int st = 256; st > 0; st >>= 1) {
                if (tid < st) red[tid] += red[tid + st];
                __syncthreads();
            }
            if (tid == 0) constv[po] = red[0] + aggb[po];
        }
        // fold M[po,k] into A-fragment-major bf16 layout
        const int pfo = po >> 4, l15 = po & 15;
        const int kend = (kq + 1) * 352;
        for (int k = kq * 352 + tid; k < kend; k += 512) {
            int c = k / 22, v = k - c * 22;
            const float* w0 = chebw + c * 64;
            float a0 = 0.f, a1 = 0.f, a2 = 0.f;
            for (int cp = 0; cp < 64; ++cp) {
                int idx = cp * 22 + v;
                a0 += w0[cp] * aggs[idx];
                a1 += w0[4096 + cp] * F1[idx];
                a2 += w0[8192 + cp] * F2[idx];
            }
            int ks = k >> 5, r = k & 31, lhi = r >> 3, jj = r & 7;
            Mfrag[(((ks * 4 + pfo) * 64) + lhi * 16 + l15) * 8 + jj] = (__bf16)(a0 + a1 + a2);
        }
    }

    // ======== grid-wide sync: Mfrag/constv visible, vmem drained ========
    cg::this_grid().sync();

    // ======== Phase C: R10 gemm loop, byte-identical structure ==========
    const int rd0 = (kg * 8) * 256 + ((((wave << 1) | 0) ^ (kg & 1)) << 4) + tcol;
    const int rd1 = (kg * 8) * 256 + ((((wave << 1) | 1) ^ (kg & 1)) << 4) + tcol;
    const __bf16* mf = Mfrag + (size_t)lane * 8;

    f32x4 acc[2][4];
#pragma unroll
    for (int m = 0; m < 2; ++m)
#pragma unroll
        for (int fo = 0; fo < 4; ++fo) acc[m][fo] = (f32x4){0.f, 0.f, 0.f, 0.f};

    auto PREFA = [&](bf16x8* dst, int ks) {
        const __bf16* p = mf + (size_t)ks * 2048;
#pragma unroll
        for (int fo = 0; fo < 4; ++fo)
            dst[fo] = *reinterpret_cast<const bf16x8*>(p + fo * 512);
    };
    auto COMPUTE = [&](const bf16x8* a, const float* buf) {
#pragma unroll
        for (int m = 0; m < 2; ++m) {
            const int rb = m ? rd1 : rd0;
            float v[8];
#pragma unroll
            for (int j = 0; j < 8; ++j) v[j] = buf[rb + j * 256];
            bf16x8 bx;
#pragma unroll
            for (int j = 0; j < 8; ++j) bx[j] = (__bf16)v[j];
#pragma unroll
            for (int fo = 0; fo < 4; ++fo)
                acc[m][fo] = __builtin_amdgcn_mfma_f32_16x16x32_bf16(a[fo], bx, acc[m][fo], 0, 0, 0);
        }
    };

    bf16x8 ac[4], an[4];
    PREFA(ac, 0);     // b0/b1 already staged (pre-sync); A(0) in flight

    // tiles 0,1: WAITV(4) is a safe no-op / partial drain (b0,b1 pre-synced;
    // A-register deps are compiler-waited). From tile 2 on, the chronology
    // [S(j), A(j), S(j+1)] matches R10's steady state exactly.
    for (int i = 0; i < 42; i += 6) {
        WAITV(4); BARR; PREFA(an, i + 1); STAGE(i + 2, b2); COMPUTE(ac, b0);
        WAITV(4); BARR; PREFA(ac, i + 2); STAGE(i + 3, b0); COMPUTE(an, b1);
        WAITV(4); BARR; PREFA(an, i + 3); STAGE(i + 4, b1); COMPUTE(ac, b2);
        WAITV(4); BARR; PREFA(ac, i + 4); STAGE(i + 5, b2); COMPUTE(an, b0);
        WAITV(4); BARR; PREFA(an, i + 5); STAGE(i + 6, b0); COMPUTE(ac, b1);
        WAITV(4); BARR; PREFA(ac, i + 6); STAGE(i + 7, b1); COMPUTE(an, b2);
    }
    WAITV(4); BARR; PREFA(an, 43); COMPUTE(ac, b0);   // tile 42
    WAITV(0); BARR; COMPUTE(an, b1);                  // tile 43

    float* yp = y + (size_t)b * (O_ * T_) + tq * 256 + wave * 32 + tcol;
#pragma unroll
    for (int m = 0; m < 2; ++m)
#pragma unroll
        for (int fo = 0; fo < 4; ++fo)
#pragma unroll
            for (int rr = 0; rr < 4; ++rr) {
                int o = fo * 16 + kg * 4 + rr;
                __builtin_nontemporal_store(acc[m][fo][rr] + constv[o],
                                            yp + (size_t)o * T_ + m * 16);
            }
}

// ---------------------------------------------------------------------------
// Fallback kernels (R10 two-launch path), used only if cooperative launch
// is rejected in this environment.
// ---------------------------------------------------------------------------
__global__ __launch_bounds__(256) void prep_all(
    const float* __restrict__ adjp,
    const float* __restrict__ chebw,
    const float* __restrict__ chebb,
    const float* __restrict__ aggw,
    const float* __restrict__ aggb,
    __bf16* __restrict__ Mfrag,
    float* __restrict__ constv)
{
    const int o   = blockIdx.x >> 2;
    const int kq  = blockIdx.x & 3;
    const int tid = threadIdx.x;
    __shared__ float sm[484];
    __shared__ float c2[484];
    __shared__ float dis[22];
    __shared__ float aggs[KTOT];
    __shared__ float F1[KTOT];
    __shared__ float F2[KTOT];
    __shared__ float red[256];

    for (int e = tid; e < 484; e += 256) {
        int i = e / 22, j = e - i * 22;
        float a = 0.5f * (1.f / (1.f + expf(-adjp[i * 22 + j])) +
                          1.f / (1.f + expf(-adjp[j * 22 + i])));
        c2[e] = (i == j) ? 0.f : a;
    }
    for (int e = tid; e < KTOT; e += 256) aggs[e] = aggw[o * KTOT + e];
    __syncthreads();
    if (tid < 22) {
        float d = 0.f;
        for (int n = 0; n < 22; ++n) d += c2[tid * 22 + n];
        dis[tid] = rsqrtf(d);
    }
    __syncthreads();
    for (int e = tid; e < 484; e += 256) {
        int i = e / 22, j = e - i * 22;
        sm[e] = -dis[i] * c2[e] * dis[j];
    }
    __syncthreads();
    for (int e = tid; e < 484; e += 256) {
        int i = e / 22, j = e - i * 22;
        float acc = 0.f;
        for (int n = 0; n < 22; ++n) acc += sm[i * 22 + n] * sm[n * 22 + j];
        c2[e] = 2.f * acc - (i == j ? 1.f : 0.f);
    }
    __syncthreads();
    for (int e = tid; e < KTOT; e += 256) {
        int cp = e / 22, v = e - cp * 22;
        float a1 = 0.f, a2 = 0.f;
        for (int n = 0; n < 22; ++n) {
            float w = aggs[cp * 22 + n];
            a1 += w * sm[n * 22 + v];
            a2 += w * c2[n * 22 + v];
        }
        F1[e] = a1;
        F2[e] = a2;
    }
    if (kq == 0) {
        float p = 0.f;
        for (int e = tid; e < KTOT; e += 256) p += aggs[e] * chebb[e / 22];
        red[tid] = p;
    }
    __syncthreads();
    if (kq == 0) {
#pragma unroll
        for (int st = 128; st > 0; st >>= 1) {
            if (tid < st) red[tid] += red[tid + st];
            __syncthreads();
        }
        if (tid == 0) constv[o] = red[0] + aggb[o];
    }
    const int fo = o >> 4, l15 = o & 15;
    const int kend = (kq + 1) * 352;
    for (int k = kq * 352 + tid; k < kend; k += 256) {
        int c = k / 22, v = k - c * 22;
        const float* w0 = chebw + c * 64;
        float a0 = 0.f, a1 = 0.f, a2 = 0.f;
        for (int cp = 0; cp < 64; ++cp) {
            int idx = cp * 22 + v;
            a0 += w0[cp] * aggs[idx];
            a1 += w0[4096 + cp] * F1[idx];
            a2 += w0[8192 + cp] * F2[idx];
        }
        int ks = k >> 5, r = k & 31, lhi = r >> 3, j = r & 7;
        Mfrag[(((ks * 4 + fo) * 64) + lhi * 16 + l15) * 8 + j] = (__bf16)(a0 + a1 + a2);
    }
}

__global__ __launch_bounds__(512, 2) void gemm_main(
    const float* __restrict__ x,
    const __bf16* __restrict__ Mfrag,
    const float* __restrict__ constv,
    float* __restrict__ y)
{
    __shared__ float lds[3 * 8192];

    const int bid  = ((blockIdx.x & 7) << 5) | (blockIdx.x >> 3);
    const int b    = bid >> 2;
    const int tq   = bid & 3;
    const int wave = threadIdx.x >> 6;
    const int lane = threadIdx.x & 63;
    const int tcol = lane & 15;
    const int kg   = lane >> 4;

    const size_t xbase = (size_t)b * ((size_t)KTOT * T_) + (size_t)tq * 256;
    const int rd0 = (kg * 8) * 256 + ((((wave << 1) | 0) ^ (kg & 1)) << 4) + tcol;
    const int rd1 = (kg * 8) * 256 + ((((wave << 1) | 1) ^ (kg & 1)) << 4) + tcol;
    const __bf16* mf = Mfrag + (size_t)lane * 8;

    f32x4 acc[2][4];
#pragma unroll
    for (int m = 0; m < 2; ++m)
#pragma unroll
        for (int fo = 0; fo < 4; ++fo) acc[m][fo] = (f32x4){0.f, 0.f, 0.f, 0.f};

    auto STAGE = [&](int ks, float* buf) {
#pragma unroll
        for (int q = 0; q < 4; ++q) {
            const int r = wave * 4 + q;
            const int s = (r >> 3) & 1;
            const int g = ((lane >> 2) ^ s);
            const float* src = x + xbase + (size_t)(ks * 32 + r) * T_
                             + g * 16 + (lane & 3) * 4;
            float* dst = buf + r * 256;
            __builtin_amdgcn_global_load_lds((const f32_g*)src, (f32_l*)dst, 16, 0, 18);
        }
    };
    auto PREFA = [&](bf16x8* dst, int ks) {
        const __bf16* p = mf + (size_t)ks * 2048;
#pragma unroll
        for (int fo = 0; fo < 4; ++fo)
            dst[fo] = *reinterpret_cast<const bf16x8*>(p + fo * 512);
    };
    auto COMPUTE = [&](const bf16x8* a, const float* buf) {
#pragma unroll
        for (int m = 0; m < 2; ++m) {
            const int rb = m ? rd1 : rd0;
            float v[8];
#pragma unroll
            for (int j = 0; j < 8; ++j) v[j] = buf[rb + j * 256];
            bf16x8 bx;
#pragma unroll
            for (int j = 0; j < 8; ++j) bx[j] = (__bf16)v[j];
#pragma unroll
            for (int fo = 0; fo < 4; ++fo)
                acc[m][fo] = __builtin_amdgcn_mfma_f32_16x16x32_bf16(a[fo], bx, acc[m][fo], 0, 0, 0);
        }
    };

    float* const b0 = lds;
    float* const b1 = lds + 8192;
    float* const b2 = lds + 16384;
    bf16x8 ac[4], an[4];

    STAGE(0, b0);
    PREFA(ac, 0);
    STAGE(1, b1);

    for (int i = 0; i < 42; i += 6) {
        WAITV(4); BARR; PREFA(an, i + 1); STAGE(i + 2, b2); COMPUTE(ac, b0);
        WAITV(4); BARR; PREFA(ac, i + 2); STAGE(i + 3, b0); COMPUTE(an, b1);
        WAITV(4); BARR; PREFA(an, i + 3); STAGE(i + 4, b1); COMPUTE(ac, b2);
        WAITV(4); BARR; PREFA(ac, i + 4); STAGE(i + 5, b2); COMPUTE(an, b0);
        WAITV(4); BARR; PREFA(an, i + 5); STAGE(i + 6, b0); COMPUTE(ac, b1);
        WAITV(4); BARR; PREFA(ac, i + 6); STAGE(i + 7, b1); COMPUTE(an, b2);
    }
    WAITV(4); BARR; PREFA(an, 43); COMPUTE(ac, b0);
    WAITV(0); BARR; COMPUTE(an, b1);

    float* yp = y + (size_t)b * (O_ * T_) + tq * 256 + wave * 32 + tcol;
#pragma unroll
    for (int m = 0; m < 2; ++m)
#pragma unroll
        for (int fo = 0; fo < 4; ++fo)
#pragma unroll
            for (int rr = 0; rr < 4; ++rr) {
                int o = fo * 16 + kg * 4 + rr;
                __builtin_nontemporal_store(acc[m][fo][rr] + constv[o],
                                            yp + (size_t)o * T_ + m * 16);
            }
}

// ---------------------------------------------------------------------------
extern "C" void kernel_launch(void* const* d_in, const int* in_sizes, int n_in,
                              void* d_out, int out_size, void* d_ws, size_t ws_size,
                              hipStream_t stream)
{
    (void)in_sizes; (void)n_in; (void)out_size; (void)ws_size;
    const float* x     = (const float*)d_in[0];
    const float* adjp  = (const float*)d_in[1];
    const float* chebw = (const float*)d_in[2];
    const float* chebb = (const float*)d_in[3];
    const float* aggw  = (const float*)d_in[4];
    const float* aggb  = (const float*)d_in[5];
    float* y = (float*)d_out;

    char* ws = (char*)d_ws;
    float*  constv = (float*)(ws);                 // 64 floats
    __bf16* Mfrag  = (__bf16*)(ws + 4096);         // 90112 bf16 (180224 B)

    void* args[] = {(void*)&x, (void*)&adjp, (void*)&chebw, (void*)&chebb,
                    (void*)&aggw, (void*)&aggb, (void*)&Mfrag, (void*)&constv,
                    (void*)&y};
    hipError_t err = hipLaunchCooperativeKernel((const void*)fused_main,
                                                dim3(256), dim3(512),
                                                args, 0, stream);
    if (err != hipSuccess) {
        // fallback: validated R10 two-kernel path
        hipLaunchKernelGGL(prep_all, dim3(256), dim3(256), 0, stream,
                           adjp, chebw, chebb, aggw, aggb, Mfrag, constv);
        hipLaunchKernelGGL(gemm_main, dim3(256), dim3(512), 0, stream,
                           x, Mfrag, constv, y);
    }
}

// Round 12
// 78.780 us; speedup vs baseline: 1.4770x; 1.4770x over previous
//
#include <hip/hip_runtime.h>
#include <hip/hip_bf16.h>

// Problem constants
#define B_    64
#define C_    64
#define N_    22
#define T_    1024
#define O_    64
#define KTOT  1408      // C_*N_
#define KSTEPS 44       // KTOT/32

typedef __bf16 bf16x8 __attribute__((ext_vector_type(8)));
typedef float  f32x4  __attribute__((ext_vector_type(4)));

typedef __attribute__((address_space(1))) float f32_g;
typedef __attribute__((address_space(3))) float f32_l;

// ---------------------------------------------------------------------------
// prep_all: grid 256 = 64 o x 4 kq (validated since R5).
// ---------------------------------------------------------------------------
__global__ __launch_bounds__(256) void prep_all(
    const float* __restrict__ adjp,
    const float* __restrict__ chebw,   // [3][64][64]
    const float* __restrict__ chebb,   // [64]
    const float* __restrict__ aggw,    // [64][64][22]
    const float* __restrict__ aggb,    // [64]
    __bf16* __restrict__ Mfrag,        // [176*512]
    float* __restrict__ constv)        // [64]
{
    const int o   = blockIdx.x >> 2;
    const int kq  = blockIdx.x & 3;
    const int tid = threadIdx.x;
    __shared__ float sm[484];
    __shared__ float c2[484];
    __shared__ float dis[22];
    __shared__ float aggs[KTOT];
    __shared__ float F1[KTOT];
    __shared__ float F2[KTOT];
    __shared__ float red[256];

    for (int e = tid; e < 484; e += 256) {
        int i = e / 22, j = e - i * 22;
        float a = 0.5f * (1.f / (1.f + expf(-adjp[i * 22 + j])) +
                          1.f / (1.f + expf(-adjp[j * 22 + i])));
        c2[e] = (i == j) ? 0.f : a;
    }
    for (int e = tid; e < KTOT; e += 256) aggs[e] = aggw[o * KTOT + e];
    __syncthreads();
    if (tid < 22) {
        float d = 0.f;
        for (int n = 0; n < 22; ++n) d += c2[tid * 22 + n];
        dis[tid] = rsqrtf(d);
    }
    __syncthreads();
    for (int e = tid; e < 484; e += 256) {
        int i = e / 22, j = e - i * 22;
        sm[e] = -dis[i] * c2[e] * dis[j];
    }
    __syncthreads();
    for (int e = tid; e < 484; e += 256) {
        int i = e / 22, j = e - i * 22;
        float acc = 0.f;
        for (int n = 0; n < 22; ++n) acc += sm[i * 22 + n] * sm[n * 22 + j];
        c2[e] = 2.f * acc - (i == j ? 1.f : 0.f);
    }
    __syncthreads();
    for (int e = tid; e < KTOT; e += 256) {
        int cp = e / 22, v = e - cp * 22;
        float a1 = 0.f, a2 = 0.f;
        for (int n = 0; n < 22; ++n) {
            float w = aggs[cp * 22 + n];
            a1 += w * sm[n * 22 + v];
            a2 += w * c2[n * 22 + v];
        }
        F1[e] = a1;
        F2[e] = a2;
    }
    if (kq == 0) {
        float p = 0.f;
        for (int e = tid; e < KTOT; e += 256) p += aggs[e] * chebb[e / 22];
        red[tid] = p;
    }
    __syncthreads();
    if (kq == 0) {
#pragma unroll
        for (int st = 128; st > 0; st >>= 1) {
            if (tid < st) red[tid] += red[tid + st];
            __syncthreads();
        }
        if (tid == 0) constv[o] = red[0] + aggb[o];
    }

    const int fo = o >> 4, l15 = o & 15;
    const int kend = (kq + 1) * 352;
    for (int k = kq * 352 + tid; k < kend; k += 256) {
        int c = k / 22, v = k - c * 22;
        const float* w0 = chebw + c * 64;
        float a0 = 0.f, a1 = 0.f, a2 = 0.f;
        for (int cp = 0; cp < 64; ++cp) {
            int idx = cp * 22 + v;
            a0 += w0[cp] * aggs[idx];
            a1 += w0[4096 + cp] * F1[idx];
            a2 += w0[8192 + cp] * F2[idx];
        }
        int ks = k >> 5, r = k & 31, lhi = r >> 3, j = r & 7;
        Mfrag[(((ks * 4 + fo) * 64) + lhi * 16 + l15) * 8 + j] = (__bf16)(a0 + a1 + a2);
    }
}

// ---------------------------------------------------------------------------
// main GEMM: R10 champion (78.8 us), byte-identical revert.
// 256 blocks = 64b x 4tq, t-tile 256, 512 threads (8 waves), 3 x 32 KB LDS
// buffers, stage distance 2, counted WAITV(4) (never 0 in main loop),
// source-side chunk-XOR swizzle, NT x-loads (aux=18), NT y-stores.
// ---------------------------------------------------------------------------
#define WAITV(N) asm volatile("s_waitcnt vmcnt(" #N ")" ::: "memory")
#define BARR do { __builtin_amdgcn_s_barrier(); __builtin_amdgcn_sched_barrier(0); } while (0)

__global__ __launch_bounds__(512, 2) void gemm_main(
    const float* __restrict__ x,
    const __bf16* __restrict__ Mfrag,
    const float* __restrict__ constv,
    float* __restrict__ y)
{
    __shared__ float lds[3 * 8192];   // 3 x [32 k][256 t] fp32 = 96 KB

    // XCD swizzle: 256 blocks -> 32 per XCD (bijective, 256 % 8 == 0)
    const int bid  = ((blockIdx.x & 7) << 5) | (blockIdx.x >> 3);
    const int b    = bid >> 2;
    const int tq   = bid & 3;
    const int wave = threadIdx.x >> 6;   // 0..7
    const int lane = threadIdx.x & 63;
    const int tcol = lane & 15;
    const int kg   = lane >> 4;

    const size_t xbase = (size_t)b * ((size_t)KTOT * T_) + (size_t)tq * 256;

    // read addressing: lane (kg,tcol), j: needs x[k=kg*8+j][t=wave*32+m*16+tcol]
    // global t-chunk G = wave*2+m stored at LDS chunk G ^ (kg&1)
    const int rd0 = (kg * 8) * 256 + ((((wave << 1) | 0) ^ (kg & 1)) << 4) + tcol;
    const int rd1 = (kg * 8) * 256 + ((((wave << 1) | 1) ^ (kg & 1)) << 4) + tcol;

    const __bf16* mf = Mfrag + (size_t)lane * 8;

    f32x4 acc[2][4];
#pragma unroll
    for (int m = 0; m < 2; ++m)
#pragma unroll
        for (int fo = 0; fo < 4; ++fo) acc[m][fo] = (f32x4){0.f, 0.f, 0.f, 0.f};

    // STAGE: wave stages rows wave*4+q (1 KB each, one gload_lds per row).
    // LDS dest wave-uniform + lane*16B (linear); source pre-swizzled.
    // aux = 18 = NT|SC1 -> non-temporal (x streamed exactly once).
    auto STAGE = [&](int ks, float* buf) {
#pragma unroll
        for (int q = 0; q < 4; ++q) {
            const int r = wave * 4 + q;
            const int s = (r >> 3) & 1;
            const int g = ((lane >> 2) ^ s);
            const float* src = x + xbase + (size_t)(ks * 32 + r) * T_
                             + g * 16 + (lane & 3) * 4;
            float* dst = buf + r * 256;              // wave-uniform base
            __builtin_amdgcn_global_load_lds((const f32_g*)src, (f32_l*)dst, 16, 0, 18);
        }
    };
    auto PREFA = [&](bf16x8* dst, int ks) {
        const __bf16* p = mf + (size_t)ks * 2048;
#pragma unroll
        for (int fo = 0; fo < 4; ++fo)
            dst[fo] = *reinterpret_cast<const bf16x8*>(p + fo * 512);
    };
    auto COMPUTE = [&](const bf16x8* a, const float* buf) {
#pragma unroll
        for (int m = 0; m < 2; ++m) {
            const int rb = m ? rd1 : rd0;
            float v[8];
#pragma unroll
            for (int j = 0; j < 8; ++j) v[j] = buf[rb + j * 256];
            bf16x8 bx;
#pragma unroll
            for (int j = 0; j < 8; ++j) bx[j] = (__bf16)v[j];
#pragma unroll
            for (int fo = 0; fo < 4; ++fo)
                acc[m][fo] = __builtin_amdgcn_mfma_f32_16x16x32_bf16(a[fo], bx, acc[m][fo], 0, 0, 0);
        }
    };

    float* const b0 = lds;
    float* const b1 = lds + 8192;
    float* const b2 = lds + 16384;
    bf16x8 ac[4], an[4];

    // ---- prologue: chronological VMEM order [S0(4), A0(4), S1(4)] ----
    STAGE(0, b0);
    PREFA(ac, 0);
    STAGE(1, b1);

    // ---- main loop: tiles 0..41 ----
    // tile j: WAITV(4) drains {S(j),A(j)}, keeps S(j+1); barrier;
    //         PREFA(j+1); STAGE(j+2); COMPUTE(j).
    for (int i = 0; i < 42; i += 6) {
        WAITV(4); BARR; PREFA(an, i + 1); STAGE(i + 2, b2); COMPUTE(ac, b0);
        WAITV(4); BARR; PREFA(ac, i + 2); STAGE(i + 3, b0); COMPUTE(an, b1);
        WAITV(4); BARR; PREFA(an, i + 3); STAGE(i + 4, b1); COMPUTE(ac, b2);
        WAITV(4); BARR; PREFA(ac, i + 4); STAGE(i + 5, b2); COMPUTE(an, b0);
        WAITV(4); BARR; PREFA(an, i + 5); STAGE(i + 6, b0); COMPUTE(ac, b1);
        WAITV(4); BARR; PREFA(ac, i + 6); STAGE(i + 7, b1); COMPUTE(an, b2);
    }

    // ---- tail: tiles 42 (b0, ac), 43 (b1, an) ----
    WAITV(4); BARR; PREFA(an, 43); COMPUTE(ac, b0);
    WAITV(0); BARR; COMPUTE(an, b1);

    // ---- store (nontemporal): o = fo*16+kg*4+rr, t = tq*256+wave*32+m*16+tcol
    float* yp = y + (size_t)b * (O_ * T_) + tq * 256 + wave * 32 + tcol;
#pragma unroll
    for (int m = 0; m < 2; ++m)
#pragma unroll
        for (int fo = 0; fo < 4; ++fo)
#pragma unroll
            for (int rr = 0; rr < 4; ++rr) {
                int o = fo * 16 + kg * 4 + rr;
                __builtin_nontemporal_store(acc[m][fo][rr] + constv[o],
                                            yp + (size_t)o * T_ + m * 16);
            }
}

// ---------------------------------------------------------------------------
extern "C" void kernel_launch(void* const* d_in, const int* in_sizes, int n_in,
                              void* d_out, int out_size, void* d_ws, size_t ws_size,
                              hipStream_t stream)
{
    (void)in_sizes; (void)n_in; (void)out_size; (void)ws_size;
    const float* x     = (const float*)d_in[0];
    const float* adjp  = (const float*)d_in[1];
    const float* chebw = (const float*)d_in[2];
    const float* chebb = (const float*)d_in[3];
    const float* aggw  = (const float*)d_in[4];
    const float* aggb  = (const float*)d_in[5];
    float* y = (float*)d_out;

    char* ws = (char*)d_ws;
    float*  constv = (float*)(ws);                 // 64 floats
    __bf16* Mfrag  = (__bf16*)(ws + 4096);         // 90112 bf16 (180224 B)

    hipLaunchKernelGGL(prep_all, dim3(256), dim3(256), 0, stream,
                       adjp, chebw, chebb, aggw, aggb, Mfrag, constv);
    hipLaunchKernelGGL(gemm_main, dim3(256), dim3(512), 0, stream,
                       x, Mfrag, constv, y);
}